// Round 7
// baseline (1583.662 us; speedup 1.0000x reference)
//
#include <hip/hip_runtime.h>

#define T_SEQ 2048
#define DIN   16
#define HH    80
#define NTHR  512
#define NBLK  256
#define BT    2
#define ROWE  192   // f16 per row: [x 0:16 | h1 16:96 | h2 96:176 | pad]

#define L2E   1.44269504088896340736f

typedef _Float16 f16x8 __attribute__((ext_vector_type(8)));
typedef float    f32x4 __attribute__((ext_vector_type(4)));

__device__ __forceinline__ float rcp_fast(float x){ return __builtin_amdgcn_rcpf(x); }
__device__ __forceinline__ float ex2(float x){
#if __has_builtin(__builtin_amdgcn_exp2f)
    return __builtin_amdgcn_exp2f(x);
#else
    return exp2f(x);
#endif
}

#define MF(av, bv, cv) __builtin_amdgcn_mfma_f32_16x16x32_f16(av, bv, cv, 0, 0, 0)
#define L1SLOT(acc, s) { acc = MF(A[s][0], B0, Q[s]); acc = MF(A[s][1], B1, acc); \
                         acc = MF(A[s][2], B2, acc); }
#define L2SLOT(acc, s) { acc = MF(A[s][0], B0, Q[s]); acc = MF(A[s][1], B1, acc); \
                         acc = MF(A[s][2], B2, acc); acc = MF(A[s][3], B3, acc); \
                         acc = MF(A[s][4], B4, acc); }

// relaxed spin on two LDS epoch counters, then acquire fence. Uniform across the
// wave (same addresses -> LDS broadcast). Bailout prevents hangs (wrong answer
// instead of dead container if the protocol has a bug).
#define SPIN2(pa, ta, pb, tb) { int _s = 0; \
    while ((__hip_atomic_load((pa), __ATOMIC_RELAXED, __HIP_MEMORY_SCOPE_WORKGROUP) < (ta)) || \
           (__hip_atomic_load((pb), __ATOMIC_RELAXED, __HIP_MEMORY_SCOPE_WORKGROUP) < (tb))) { \
        if (++_s > (1<<14)) break; } \
    __builtin_amdgcn_fence(__ATOMIC_ACQUIRE, "workgroup"); }

#define SIGNAL(p) if (lane == 0) \
    __hip_atomic_fetch_add((p), 1, __ATOMIC_RELEASE, __HIP_MEMORY_SCOPE_WORKGROUP)

__global__
__attribute__((amdgpu_flat_work_group_size(NTHR, NTHR)))
__attribute__((amdgpu_waves_per_eu(2, 2)))
void lstm2_flag(
    const float* __restrict__ x,
    const float* __restrict__ W_ih1, const float* __restrict__ W_hh1,
    const float* __restrict__ b_ih1, const float* __restrict__ b_hh1,
    const float* __restrict__ W_ih2, const float* __restrict__ W_hh2,
    const float* __restrict__ b_ih2, const float* __restrict__ b_hh2,
    const float* __restrict__ W_d,   const float* __restrict__ b_d,
    float* __restrict__ out)
{
    __shared__ __align__(16) _Float16 HB[2][BT][ROWE];   // [parity][batch][x|h1|h2]
    __shared__ int W1c;   // L1 wave-window completions (incl. x staging)
    __shared__ int W2c;   // L2 wave-window completions
    __shared__ int RD2c;  // L2 wave-window READ completions (fires early)

    const int t    = threadIdx.x;
    const int lane = t & 63;
    const int wv   = t >> 6;              // 0..7 ; wv&3 = SIMD
    const bool isL1w = (wv < 4);
    const int m16  = lane & 15;
    const int kgrp = lane >> 4;           // 0..3
    const int b0   = blockIdx.x * BT;

    const int uloc = isL1w ? 20*wv : 20*(wv-4);

    // ---------------- stationary A fragments + bias-in-C ----------------
    // A row m in tile: unit = 4*tile + (m>>2), gate = m&3 (i,f,g,o interleaved)
    f16x8 A[5][5];
    f32x4 Q[5];
    {
        const int g  = m16 & 3;
        const int ut = m16 >> 2;
        const float sc = (g == 2) ? (2.f*L2E) : L2E;       // tanh gate: 2*log2e
        #pragma unroll
        for (int s = 0; s < 5; ++s) {
            const int grow = g*HH + (uloc + 4*s + ut);
            #pragma unroll
            for (int c = 0; c < 5; ++c) {
                if (isL1w && c >= 3) continue;             // L1 K=96: 3 chunks
                f16x8 a;
                #pragma unroll
                for (int j = 0; j < 8; ++j) {
                    const int kk = 32*c + 8*kgrp + j;
                    const float v = isL1w
                        ? ((kk < DIN) ? W_ih1[(size_t)grow*DIN + kk]
                                      : W_hh1[(size_t)grow*HH + (kk - DIN)])
                        : ((kk < HH)  ? W_ih2[(size_t)grow*HH + kk]
                                      : W_hh2[(size_t)grow*HH + (kk - HH)]);
                    a[j] = (_Float16)(v * sc);
                }
                A[s][c] = a;
            }
            const int u = uloc + 4*s + kgrp;
            const float* bI = isL1w ? b_ih1 : b_ih2;
            const float* bH = isL1w ? b_hh1 : b_hh2;
            f32x4 bb;
            bb[0] = (bI[       u] + bH[       u]) * L2E;
            bb[1] = (bI[  HH + u] + bH[  HH + u]) * L2E;
            bb[2] = (bI[2*HH + u] + bH[2*HH + u]) * (2.f*L2E);
            bb[3] = (bI[3*HH + u] + bH[3*HH + u]) * L2E;
            Q[s] = bb;
        }
    }

    // ---------------- merged-epilogue per-lane identity ----------------
    const int  te      = m16 >> 1;
    const bool act_ep  = (m16 < 10);
    const int  unit_ep = uloc + 4*(act_ep ? te : 0) + kgrp;
    const int  seg     = isL1w ? DIN : (DIN + HH);          // h1 at 16, h2 at 96
    const int  batch_ep = lane & 1;

    // ---------------- init state, flags, x prefetch ----------------
    for (int i = t; i < 2*BT*ROWE; i += NTHR) ((_Float16*)HB)[i] = (_Float16)0.f;
    if (t == 0) { W1c = 0; W2c = 0; RD2c = 0; }

    const int xbn = (lane >> 4) & 1;
    const int xch = lane & 15;
    const float* xptr = x + ((size_t)(b0 + xbn) * T_SEQ) * DIN + xch;
    float xa = 0.f, xbv = 0.f, xcv = 0.f;
    if (wv == 0 && lane < 32) {
        HB[0][xbn][xch] = (_Float16)xptr[0];
        xa  = xptr[1*DIN];
        xbv = xptr[2*DIN];
        xcv = xptr[3*DIN];
    }
    __syncthreads();   // one-time: state+flags visible; no barriers after this

    float cst = 0.f;   // cell state for this lane's (unit,batch)

    // window k: L1 computes h1(k) from [x(k)|h1(k-1)]@pb -> @nb
    //           L2 computes h2(k-1) from [h1(k-1)|h2(k-2)]@pb -> @nb
    #pragma unroll 1
    for (int k = 0; k <= T_SEQ; ++k) {
        const int pb = k & 1, nb = pb ^ 1;

        if (isL1w) {
            // need: h1(k-1)+x(k) published (W1>=4k); L2 done READING window k-1 (RD2>=4k)
            SPIN2(&W1c, 4*k, &RD2c, 4*k);

            if (wv == 0 && lane < 32) {        // stage x(k+1) -> nb
                HB[nb][xbn][xch] = (_Float16)xa;
                xa = xbv; xbv = xcv;
                const int tn = (k + 4 < T_SEQ) ? (k + 4) : (T_SEQ - 1);
                xcv = xptr[(size_t)tn * DIN];
            }

            if (k < T_SEQ) {
                const _Float16* rb = &HB[pb][lane & 1][0];
                const f16x8 B0 = *(const f16x8*)(rb +       8*kgrp);  // x | h1[0:16)
                const f16x8 B1 = *(const f16x8*)(rb +  32 + 8*kgrp);  // h1[16:48)
                const f16x8 B2 = *(const f16x8*)(rb +  64 + 8*kgrp);  // h1[48:80)
                f32x4 acc0, acc1, acc2, acc3, acc4;
                L1SLOT(acc0, 0) L1SLOT(acc1, 1) L1SLOT(acc2, 2)
                L1SLOT(acc3, 3) L1SLOT(acc4, 4)

                float M0 = acc0[0], M1 = acc0[1], M2 = acc0[2], M3 = acc0[3];
                if (te == 1) { M0 = acc1[0]; M1 = acc1[1]; M2 = acc1[2]; M3 = acc1[3]; }
                if (te == 2) { M0 = acc2[0]; M1 = acc2[1]; M2 = acc2[2]; M3 = acc2[3]; }
                if (te == 3) { M0 = acc3[0]; M1 = acc3[1]; M2 = acc3[2]; M3 = acc3[3]; }
                if (te == 4) { M0 = acc4[0]; M1 = acc4[1]; M2 = acc4[2]; M3 = acc4[3]; }

                const float iv = rcp_fast(1.f + ex2(-M0));
                const float fv = rcp_fast(1.f + ex2(-M1));
                const float gv = 1.f - 2.f*rcp_fast(1.f + ex2(M2));
                const float ov = rcp_fast(1.f + ex2(-M3));
                cst = fv*cst + iv*gv;
                const float tc = 1.f - 2.f*rcp_fast(1.f + ex2(cst * (2.f*L2E)));
                if (act_ep)
                    HB[nb][batch_ep][seg + unit_ep] = (_Float16)(ov * tc);
            }
            asm volatile("s_waitcnt lgkmcnt(0)" ::: "memory");
            SIGNAL(&W1c);                      // h1(k)+x(k+1) published
        } else {
            // need: h1(k-1) published (W1>=4k); own group done window k-1 (W2>=4k)
            SPIN2(&W1c, 4*k, &W2c, 4*k);

            f16x8 B0{}, B1{}, B2{}, B3{}, B4{};
            if (k >= 1) {
                const _Float16* rb = &HB[pb][lane & 1][0];
                B0 = *(const f16x8*)(rb +  16 + 8*kgrp);   // h1[0:32)
                B1 = *(const f16x8*)(rb +  48 + 8*kgrp);   // h1[32:64)
                B2 = *(const f16x8*)(rb +  80 + 8*kgrp);   // h1[64:80)|h2[0:16)
                B3 = *(const f16x8*)(rb + 112 + 8*kgrp);   // h2[16:48)
                B4 = *(const f16x8*)(rb + 144 + 8*kgrp);   // h2[48:80)
            }
            asm volatile("s_waitcnt lgkmcnt(0)" ::: "memory");
            SIGNAL(&RD2c);                     // done reading window k-1 buffers

            if (k >= 1) {
                f32x4 acc0, acc1, acc2, acc3, acc4;
                L2SLOT(acc0, 0) L2SLOT(acc1, 1) L2SLOT(acc2, 2)
                L2SLOT(acc3, 3) L2SLOT(acc4, 4)

                float M0 = acc0[0], M1 = acc0[1], M2 = acc0[2], M3 = acc0[3];
                if (te == 1) { M0 = acc1[0]; M1 = acc1[1]; M2 = acc1[2]; M3 = acc1[3]; }
                if (te == 2) { M0 = acc2[0]; M1 = acc2[1]; M2 = acc2[2]; M3 = acc2[3]; }
                if (te == 3) { M0 = acc3[0]; M1 = acc3[1]; M2 = acc3[2]; M3 = acc3[3]; }
                if (te == 4) { M0 = acc4[0]; M1 = acc4[1]; M2 = acc4[2]; M3 = acc4[3]; }

                const float iv = rcp_fast(1.f + ex2(-M0));
                const float fv = rcp_fast(1.f + ex2(-M1));
                const float gv = 1.f - 2.f*rcp_fast(1.f + ex2(M2));
                const float ov = rcp_fast(1.f + ex2(-M3));
                cst = fv*cst + iv*gv;
                const float tc = 1.f - 2.f*rcp_fast(1.f + ex2(cst * (2.f*L2E)));
                if (act_ep)
                    HB[nb][batch_ep][seg + unit_ep] = (_Float16)(ov * tc);
            }
            asm volatile("s_waitcnt lgkmcnt(0)" ::: "memory");
            SIGNAL(&W2c);                      // h2(k-1) published
        }
    }

    // ---- dense head: out[b] = W_d . h2(T-1) + b_d ; h2(T-1) in parity 1 ----
    if (wv == 0) {
        SPIN2(&W2c, 4*(T_SEQ+1), &W1c, 0);    // wait for final h2 publication
        float a0 = 0.f, a1 = 0.f;
        for (int u = lane; u < HH; u += 64) {
            const float wd = W_d[u];
            a0 += wd * (float)HB[1][0][DIN + HH + u];
            a1 += wd * (float)HB[1][1][DIN + HH + u];
        }
        #pragma unroll
        for (int off = 32; off > 0; off >>= 1) {
            a0 += __shfl_down(a0, off);
            a1 += __shfl_down(a1, off);
        }
        if (lane == 0) { out[b0] = a0 + b_d[0]; out[b0 + 1] = a1 + b_d[0]; }
    }
}

extern "C" void kernel_launch(void* const* d_in, const int* in_sizes, int n_in,
                              void* d_out, int out_size, void* d_ws, size_t ws_size,
                              hipStream_t stream) {
    const float* x     = (const float*)d_in[0];
    const float* W_ih1 = (const float*)d_in[1];
    const float* W_hh1 = (const float*)d_in[2];
    const float* b_ih1 = (const float*)d_in[3];
    const float* b_hh1 = (const float*)d_in[4];
    const float* W_ih2 = (const float*)d_in[5];
    const float* W_hh2 = (const float*)d_in[6];
    const float* b_ih2 = (const float*)d_in[7];
    const float* b_hh2 = (const float*)d_in[8];
    const float* W_d   = (const float*)d_in[9];
    const float* b_d   = (const float*)d_in[10];

    lstm2_flag<<<NBLK, NTHR, 0, stream>>>(x, W_ih1, W_hh1, b_ih1, b_hh1,
                                          W_ih2, W_hh2, b_ih2, b_hh2,
                                          W_d, b_d, (float*)d_out);
}

// Round 8
// 1447.019 us; speedup vs baseline: 1.0944x; 1.0944x over previous
//
#include <hip/hip_runtime.h>

#define T_SEQ 2048
#define DIN   16
#define HH    80
#define NTHR  512
#define NBLK  256
#define BT    2
#define ROWE  192   // f16 per row: [x 0:16 | h1 16:96 | h2 96:176 | pad]

#define L2E   1.44269504088896340736f

typedef _Float16 f16x8 __attribute__((ext_vector_type(8)));
typedef float    f32x4 __attribute__((ext_vector_type(4)));

__device__ __forceinline__ float rcp_fast(float x){ return __builtin_amdgcn_rcpf(x); }
__device__ __forceinline__ float ex2(float x){
#if __has_builtin(__builtin_amdgcn_exp2f)
    return __builtin_amdgcn_exp2f(x);
#else
    return exp2f(x);
#endif
}

#define MF(av, bv, cv) __builtin_amdgcn_mfma_f32_16x16x32_f16(av, bv, cv, 0, 0, 0)
#define FA(i) __builtin_bit_cast(f16x8, AV[i])
#define FQ(s) __builtin_bit_cast(f32x4, QV[s])

// L1 slot: 3 K-chunks over [x(16)|h1(80)]; bias pre-loaded in C
#define L1SLOT(acc, s) { acc = MF(FA(s*5+0), B0, FQ(s)); acc = MF(FA(s*5+1), B1, acc); \
                         acc = MF(FA(s*5+2), B2, acc); }
// L2 slot: 5 K-chunks over [h1(80)|h2(80)]; bias pre-loaded in C
#define L2SLOT(acc, s) { acc = MF(FA(s*5+0), B0, FQ(s)); acc = MF(FA(s*5+1), B1, acc); \
                         acc = MF(FA(s*5+2), B2, acc); acc = MF(FA(s*5+3), B3, acc); \
                         acc = MF(FA(s*5+4), B4, acc); }

// anti-AGPR-stash: force arch-VGPR residency every iteration (R0's proven trick)
#define PIN4(v) asm volatile("" : "+v"(v.x), "+v"(v.y), "+v"(v.z), "+v"(v.w))
#define PIN_ALL { PIN4(AV[0]);  PIN4(AV[1]);  PIN4(AV[2]);  PIN4(AV[3]);  PIN4(AV[4]);  \
                  PIN4(AV[5]);  PIN4(AV[6]);  PIN4(AV[7]);  PIN4(AV[8]);  PIN4(AV[9]);  \
                  PIN4(AV[10]); PIN4(AV[11]); PIN4(AV[12]); PIN4(AV[13]); PIN4(AV[14]); \
                  PIN4(AV[15]); PIN4(AV[16]); PIN4(AV[17]); PIN4(AV[18]); PIN4(AV[19]); \
                  PIN4(AV[20]); PIN4(AV[21]); PIN4(AV[22]); PIN4(AV[23]); PIN4(AV[24]); \
                  PIN4(QV[0]);  PIN4(QV[1]);  PIN4(QV[2]);  PIN4(QV[3]);  PIN4(QV[4]); }

__global__
__attribute__((amdgpu_flat_work_group_size(NTHR, NTHR)))
__attribute__((amdgpu_waves_per_eu(2, 2)))
void lstm2_mfma(
    const float* __restrict__ x,
    const float* __restrict__ W_ih1, const float* __restrict__ W_hh1,
    const float* __restrict__ b_ih1, const float* __restrict__ b_hh1,
    const float* __restrict__ W_ih2, const float* __restrict__ W_hh2,
    const float* __restrict__ b_ih2, const float* __restrict__ b_hh2,
    const float* __restrict__ W_d,   const float* __restrict__ b_d,
    float* __restrict__ out)
{
    __shared__ __align__(16) _Float16 HB[2][BT][ROWE];   // [parity][batch][x|h1|h2]

    const int t    = threadIdx.x;
    const int lane = t & 63;
    const int wv   = t >> 6;              // 0..7 ; wv&3 = SIMD
    const bool isL1w = (wv < 4);          // waves 0-3: layer1, 4-7: layer2
    const int m16  = lane & 15;
    const int kgrp = lane >> 4;           // 0..3
    const int b0   = blockIdx.x * BT;

    const int uloc = isL1w ? 20*wv : 20*(wv-4);   // first unit of this wave's 5 tiles

    // ---------------- stationary A fragments + bias-in-C, held as pinned float4 ----------------
    // A row m in tile: unit = 4*tile + (m>>2), gate = m&3 (i,f,g,o interleaved)
    // C rows: 4*kgrp + gate -> QV[s] = biases for unit (uloc+4s+kgrp), pre-scaled by log2e
    float4 AV[25];
    float4 QV[5];
    {
        const int g  = m16 & 3;
        const int ut = m16 >> 2;
        const float sc = (g == 2) ? (2.f*L2E) : L2E;       // tanh gate: 2*log2e
        #pragma unroll
        for (int s = 0; s < 5; ++s) {
            const int grow = g*HH + (uloc + 4*s + ut);
            #pragma unroll
            for (int c = 0; c < 5; ++c) {
                if (isL1w && c >= 3) { AV[s*5+c] = make_float4(0.f,0.f,0.f,0.f); continue; }
                f16x8 a;
                #pragma unroll
                for (int j = 0; j < 8; ++j) {
                    const int kk = 32*c + 8*kgrp + j;
                    const float v = isL1w
                        ? ((kk < DIN) ? W_ih1[(size_t)grow*DIN + kk]
                                      : W_hh1[(size_t)grow*HH + (kk - DIN)])
                        : ((kk < HH)  ? W_ih2[(size_t)grow*HH + kk]
                                      : W_hh2[(size_t)grow*HH + (kk - HH)]);
                    a[j] = (_Float16)(v * sc);
                }
                AV[s*5+c] = __builtin_bit_cast(float4, a);
            }
            const int u = uloc + 4*s + kgrp;
            const float* bI = isL1w ? b_ih1 : b_ih2;
            const float* bH = isL1w ? b_hh1 : b_hh2;
            QV[s] = make_float4((bI[       u] + bH[       u]) * L2E,
                                (bI[  HH + u] + bH[  HH + u]) * L2E,
                                (bI[2*HH + u] + bH[2*HH + u]) * (2.f*L2E),
                                (bI[3*HH + u] + bH[3*HH + u]) * L2E);
        }
    }

    // ---------------- merged-epilogue per-lane identity ----------------
    const int  te      = m16 >> 1;
    const bool act_ep  = (m16 < 10);
    const int  unit_ep = uloc + 4*(act_ep ? te : 0) + kgrp;
    const int  seg     = isL1w ? DIN : (DIN + HH);          // h1 at 16, h2 at 96
    const int  batch_ep = lane & 1;

    // ---------------- zero state, prime x pipeline (depth-3 prefetch) ----------------
    for (int i = t; i < 2*BT*ROWE; i += NTHR) ((_Float16*)HB)[i] = (_Float16)0.f;
    __syncthreads();

    const int xbn = (lane >> 4) & 1;
    const int xch = lane & 15;
    const float* xptr = x + ((size_t)(b0 + xbn) * T_SEQ) * DIN + xch;
    float xa = 0.f, xbv = 0.f, xcv = 0.f;
    if (wv == 0 && lane < 32) {
        HB[0][xbn][xch] = (_Float16)xptr[0];
        xa  = xptr[1*DIN];
        xbv = xptr[2*DIN];
        xcv = xptr[3*DIN];
    }
    __syncthreads();

    float cst = 0.f;   // cell state for this lane's (unit,batch)

    // window k: L1 computes h1(k) from [x(k)|h1(k-1)]@pb -> @nb
    //           L2 computes h2(k-1) from [h1(k-1)|h2(k-2)]@pb -> @nb
    #pragma unroll 1
    for (int k = 0; k <= T_SEQ; ++k) {
        const int pb = k & 1, nb = pb ^ 1;
        PIN_ALL;   // anti-AGPR-stash: weights stay in arch VGPRs across the barrier

        if (wv == 0 && lane < 32) {          // stage x(k+1) -> nb
            HB[nb][xbn][xch] = (_Float16)xa;
            xa = xbv; xbv = xcv;
            const int tn = (k + 4 < T_SEQ) ? (k + 4) : (T_SEQ - 1);
            xcv = xptr[(size_t)tn * DIN];
        }

        const bool act = isL1w ? (k < T_SEQ) : (k >= 1);
        if (act) {
            const _Float16* rb = &HB[pb][lane & 1][0];     // B col n <- batch n&1
            f32x4 acc0, acc1, acc2, acc3, acc4;
            if (isL1w) {
                const f16x8 B0 = *(const f16x8*)(rb +       8*kgrp);  // x | h1[0:16)
                const f16x8 B1 = *(const f16x8*)(rb +  32 + 8*kgrp);  // h1[16:48)
                const f16x8 B2 = *(const f16x8*)(rb +  64 + 8*kgrp);  // h1[48:80)
                L1SLOT(acc0, 0) L1SLOT(acc1, 1) L1SLOT(acc2, 2)
                L1SLOT(acc3, 3) L1SLOT(acc4, 4)
            } else {
                const f16x8 B0 = *(const f16x8*)(rb +  16 + 8*kgrp);  // h1[0:32)
                const f16x8 B1 = *(const f16x8*)(rb +  48 + 8*kgrp);  // h1[32:64)
                const f16x8 B2 = *(const f16x8*)(rb +  80 + 8*kgrp);  // h1[64:80)|h2[0:16)
                const f16x8 B3 = *(const f16x8*)(rb + 112 + 8*kgrp);  // h2[16:48)
                const f16x8 B4 = *(const f16x8*)(rb + 144 + 8*kgrp);  // h2[48:80)
                L2SLOT(acc0, 0) L2SLOT(acc1, 1) L2SLOT(acc2, 2)
                L2SLOT(acc3, 3) L2SLOT(acc4, 4)
            }

            // in-register merge: pick own slot's (i,f,g,o) — cndmask chain
            float M0 = acc0[0], M1 = acc0[1], M2 = acc0[2], M3 = acc0[3];
            if (te == 1) { M0 = acc1[0]; M1 = acc1[1]; M2 = acc1[2]; M3 = acc1[3]; }
            if (te == 2) { M0 = acc2[0]; M1 = acc2[1]; M2 = acc2[2]; M3 = acc2[3]; }
            if (te == 3) { M0 = acc3[0]; M1 = acc3[1]; M2 = acc3[2]; M3 = acc3[3]; }
            if (te == 4) { M0 = acc4[0]; M1 = acc4[1]; M2 = acc4[2]; M3 = acc4[3]; }

            // activations (bias + log2e scaling already folded into C-init / weights)
            const float iv = rcp_fast(1.f + ex2(-M0));
            const float fv = rcp_fast(1.f + ex2(-M1));
            const float gv = 1.f - 2.f*rcp_fast(1.f + ex2(M2));
            const float ov = rcp_fast(1.f + ex2(-M3));
            cst = fv*cst + iv*gv;
            const float tc = 1.f - 2.f*rcp_fast(1.f + ex2(cst * (2.f*L2E)));
            if (act_ep)
                HB[nb][batch_ep][seg + unit_ep] = (_Float16)(ov * tc);
        }
        __syncthreads();
    }

    // ---- dense head: out[b] = W_d . h2(T-1) + b_d ; h2(T-1) in parity 1 ----
    if (wv == 0) {
        float a0 = 0.f, a1 = 0.f;
        for (int u = lane; u < HH; u += 64) {
            const float wd = W_d[u];
            a0 += wd * (float)HB[1][0][DIN + HH + u];
            a1 += wd * (float)HB[1][1][DIN + HH + u];
        }
        #pragma unroll
        for (int off = 32; off > 0; off >>= 1) {
            a0 += __shfl_down(a0, off);
            a1 += __shfl_down(a1, off);
        }
        if (lane == 0) { out[b0] = a0 + b_d[0]; out[b0 + 1] = a1 + b_d[0]; }
    }
}

extern "C" void kernel_launch(void* const* d_in, const int* in_sizes, int n_in,
                              void* d_out, int out_size, void* d_ws, size_t ws_size,
                              hipStream_t stream) {
    const float* x     = (const float*)d_in[0];
    const float* W_ih1 = (const float*)d_in[1];
    const float* W_hh1 = (const float*)d_in[2];
    const float* b_ih1 = (const float*)d_in[3];
    const float* b_hh1 = (const float*)d_in[4];
    const float* W_ih2 = (const float*)d_in[5];
    const float* W_hh2 = (const float*)d_in[6];
    const float* b_ih2 = (const float*)d_in[7];
    const float* b_hh2 = (const float*)d_in[8];
    const float* W_d   = (const float*)d_in[9];
    const float* b_d   = (const float*)d_in[10];

    lstm2_mfma<<<NBLK, NTHR, 0, stream>>>(x, W_ih1, W_hh1, b_ih1, b_hh1,
                                          W_ih2, W_hh2, b_ih2, b_hh2,
                                          W_d, b_d, (float*)d_out);
}

// Round 9
// 1430.354 us; speedup vs baseline: 1.1072x; 1.0117x over previous
//
#include <hip/hip_runtime.h>

#define T_SEQ 2048
#define DIN   16
#define HH    80
#define NTHR  512
#define NBLK  256
#define BT    2
#define ROWE  160   // f16 per row: [h1 0:80 | h2 80:160]

#define L2E   1.44269504088896340736f

typedef _Float16 f16x8 __attribute__((ext_vector_type(8)));
typedef float    f32x4 __attribute__((ext_vector_type(4)));

__device__ __forceinline__ float rcp_fast(float x){ return __builtin_amdgcn_rcpf(x); }
__device__ __forceinline__ float ex2(float x){
#if __has_builtin(__builtin_amdgcn_exp2f)
    return __builtin_amdgcn_exp2f(x);
#else
    return exp2f(x);
#endif
}

#define MF(av, bv, cv) __builtin_amdgcn_mfma_f32_16x16x32_f16(av, bv, cv, 0, 0, 0)
// L1 slot: 3 K-chunks over [x(16)|h1(80)]; bias pre-loaded in C
#define L1SLOT(acc, s) { acc = MF(A[s][0], B0, Q[s]); acc = MF(A[s][1], B1, acc); \
                         acc = MF(A[s][2], B2, acc); }
// L2 slot: 5 K-chunks over [h1(80)|h2(80)]; bias pre-loaded in C
#define L2SLOT(acc, s) { acc = MF(A[s][0], B0, Q[s]); acc = MF(A[s][1], B1, acc); \
                         acc = MF(A[s][2], B2, acc); acc = MF(A[s][3], B3, acc); \
                         acc = MF(A[s][4], B4, acc); }

__global__
__attribute__((amdgpu_flat_work_group_size(NTHR, NTHR)))
__attribute__((amdgpu_waves_per_eu(2, 2)))
void lstm2_pre(
    const float* __restrict__ x,
    const float* __restrict__ W_ih1, const float* __restrict__ W_hh1,
    const float* __restrict__ b_ih1, const float* __restrict__ b_hh1,
    const float* __restrict__ W_ih2, const float* __restrict__ W_hh2,
    const float* __restrict__ b_ih2, const float* __restrict__ b_hh2,
    const float* __restrict__ W_d,   const float* __restrict__ b_d,
    float* __restrict__ out)
{
    __shared__ __align__(16) _Float16 XA[T_SEQ][BT][DIN];  // full x sequence, f16 (128 KB)
    __shared__ __align__(16) _Float16 HB[2][BT][ROWE];     // [parity][batch][h1|h2]

    const int t    = threadIdx.x;
    const int lane = t & 63;
    const int wv   = t >> 6;              // 0..7 ; wv&3 = SIMD
    const bool isL1w = (wv < 4);          // waves 0-3: layer1, 4-7: layer2
    const int m16  = lane & 15;
    const int kgrp = lane >> 4;           // 0..3
    const int b0   = blockIdx.x * BT;

    const int uloc = isL1w ? 20*wv : 20*(wv-4);   // first unit of this wave's 5 tiles

    // ---------------- stationary A fragments + bias-in-C ----------------
    // A row m in tile: unit = 4*tile + (m>>2), gate = m&3 (i,f,g,o interleaved)
    // C rows: 4*kgrp + gate -> Q[s] = biases for unit (uloc+4s+kgrp), pre-scaled by log2e
    f16x8 A[5][5];
    f32x4 Q[5];
    {
        const int g  = m16 & 3;
        const int ut = m16 >> 2;
        const float sc = (g == 2) ? (2.f*L2E) : L2E;       // tanh gate: 2*log2e
        #pragma unroll
        for (int s = 0; s < 5; ++s) {
            const int grow = g*HH + (uloc + 4*s + ut);
            #pragma unroll
            for (int c = 0; c < 5; ++c) {
                if (isL1w && c >= 3) continue;             // L1 K=96: 3 chunks
                f16x8 a;
                #pragma unroll
                for (int j = 0; j < 8; ++j) {
                    const int kk = 32*c + 8*kgrp + j;
                    const float v = isL1w
                        ? ((kk < DIN) ? W_ih1[(size_t)grow*DIN + kk]
                                      : W_hh1[(size_t)grow*HH + (kk - DIN)])
                        : ((kk < HH)  ? W_ih2[(size_t)grow*HH + kk]
                                      : W_hh2[(size_t)grow*HH + (kk - HH)]);
                    a[j] = (_Float16)(v * sc);
                }
                A[s][c] = a;
            }
            const int u = uloc + 4*s + kgrp;
            const float* bI = isL1w ? b_ih1 : b_ih2;
            const float* bH = isL1w ? b_hh1 : b_hh2;
            f32x4 bb;
            bb[0] = (bI[       u] + bH[       u]) * L2E;
            bb[1] = (bI[  HH + u] + bH[  HH + u]) * L2E;
            bb[2] = (bI[2*HH + u] + bH[2*HH + u]) * (2.f*L2E);
            bb[3] = (bI[3*HH + u] + bH[3*HH + u]) * L2E;
            Q[s] = bb;
        }
    }

    // ---------------- merged-epilogue per-lane identity ----------------
    const int  te      = m16 >> 1;
    const bool act_ep  = (m16 < 10);
    const int  unit_ep = uloc + 4*(act_ep ? te : 0) + kgrp;
    const int  seg     = isL1w ? 0 : HH;                   // h1 at 0, h2 at 80
    const int  batch_ep = lane & 1;

    // ---------------- zero h state; preload ENTIRE x into LDS (f16) ----------------
    for (int i = t; i < 2*BT*ROWE; i += NTHR) ((_Float16*)HB)[i] = (_Float16)0.f;

    for (int i = t; i < T_SEQ*BT; i += NTHR) {             // 4096 rows / 512 thr = 8 iters
        const int kk = i >> 1, bb = i & 1;
        const float* xs = x + ((size_t)(b0 + bb)*T_SEQ + kk)*DIN;
        const float4 v0 = ((const float4*)xs)[0];
        const float4 v1 = ((const float4*)xs)[1];
        const float4 v2 = ((const float4*)xs)[2];
        const float4 v3 = ((const float4*)xs)[3];
        f16x8 h0, h1;
        h0[0]=(_Float16)v0.x; h0[1]=(_Float16)v0.y; h0[2]=(_Float16)v0.z; h0[3]=(_Float16)v0.w;
        h0[4]=(_Float16)v1.x; h0[5]=(_Float16)v1.y; h0[6]=(_Float16)v1.z; h0[7]=(_Float16)v1.w;
        h1[0]=(_Float16)v2.x; h1[1]=(_Float16)v2.y; h1[2]=(_Float16)v2.z; h1[3]=(_Float16)v2.w;
        h1[4]=(_Float16)v3.x; h1[5]=(_Float16)v3.y; h1[6]=(_Float16)v3.z; h1[7]=(_Float16)v3.w;
        *(f16x8*)&XA[kk][bb][0] = h0;
        *(f16x8*)&XA[kk][bb][8] = h1;
    }
    __syncthreads();

    float cst = 0.f;                       // cell state for this lane's (unit,batch)
    const bool xlane = (kgrp < 2);         // L1 B0: kgrp 0,1 <- x ; kgrp 2,3 <- h1[0:16)
    const _Float16* const hbp[2] = { &HB[0][lane & 1][0], &HB[1][lane & 1][0] };

    // window k: L1 computes h1(k) from [x(k)|h1(k-1)]@pb -> @nb
    //           L2 computes h2(k-1) from [h1(k-1)|h2(k-2)]@pb -> @nb
    #pragma unroll 1
    for (int k = 0; k <= T_SEQ; ++k) {
        const int pb = k & 1, nb = pb ^ 1;
        const _Float16* rb = hbp[pb];

        const bool act = isL1w ? (k < T_SEQ) : (k >= 1);
        if (act) {
            f32x4 acc0, acc1, acc2, acc3, acc4;
            if (isL1w) {
                const _Float16* p0 = xlane ? &XA[k][lane & 1][8*kgrp]
                                           : (rb + 8*kgrp - 16);
                const f16x8 B0 = *(const f16x8*)p0;                   // x | h1[0:16)
                const f16x8 B1 = *(const f16x8*)(rb + 16 + 8*kgrp);   // h1[16:48)
                const f16x8 B2 = *(const f16x8*)(rb + 48 + 8*kgrp);   // h1[48:80)
                L1SLOT(acc0, 0) L1SLOT(acc1, 1) L1SLOT(acc2, 2)
                L1SLOT(acc3, 3) L1SLOT(acc4, 4)
            } else {
                const f16x8 B0 = *(const f16x8*)(rb +       8*kgrp);  // h1[0:32)
                const f16x8 B1 = *(const f16x8*)(rb +  32 + 8*kgrp);  // h1[32:64)
                const f16x8 B2 = *(const f16x8*)(rb +  64 + 8*kgrp);  // h1[64:80)|h2[0:16)
                const f16x8 B3 = *(const f16x8*)(rb +  96 + 8*kgrp);  // h2[16:48)
                const f16x8 B4 = *(const f16x8*)(rb + 128 + 8*kgrp);  // h2[48:80)
                L2SLOT(acc0, 0) L2SLOT(acc1, 1) L2SLOT(acc2, 2)
                L2SLOT(acc3, 3) L2SLOT(acc4, 4)
            }

            // in-register merge: pick own slot's (i,f,g,o) — cndmask chain
            float M0 = acc0[0], M1 = acc0[1], M2 = acc0[2], M3 = acc0[3];
            if (te == 1) { M0 = acc1[0]; M1 = acc1[1]; M2 = acc1[2]; M3 = acc1[3]; }
            if (te == 2) { M0 = acc2[0]; M1 = acc2[1]; M2 = acc2[2]; M3 = acc2[3]; }
            if (te == 3) { M0 = acc3[0]; M1 = acc3[1]; M2 = acc3[2]; M3 = acc3[3]; }
            if (te == 4) { M0 = acc4[0]; M1 = acc4[1]; M2 = acc4[2]; M3 = acc4[3]; }

            // activations (bias + log2e scaling already folded into C-init / weights)
            const float iv = rcp_fast(1.f + ex2(-M0));
            const float fv = rcp_fast(1.f + ex2(-M1));
            const float gv = 1.f - 2.f*rcp_fast(1.f + ex2(M2));
            const float ov = rcp_fast(1.f + ex2(-M3));
            cst = fv*cst + iv*gv;
            const float tc = 1.f - 2.f*rcp_fast(1.f + ex2(cst * (2.f*L2E)));
            if (act_ep)
                HB[nb][batch_ep][seg + unit_ep] = (_Float16)(ov * tc);
        }
        __syncthreads();
    }

    // ---- dense head: out[b] = W_d . h2(T-1) + b_d ; h2(T-1) in parity 1 ----
    if (wv == 0) {
        float a0 = 0.f, a1 = 0.f;
        for (int u = lane; u < HH; u += 64) {
            const float wd = W_d[u];
            a0 += wd * (float)HB[1][0][HH + u];
            a1 += wd * (float)HB[1][1][HH + u];
        }
        #pragma unroll
        for (int off = 32; off > 0; off >>= 1) {
            a0 += __shfl_down(a0, off);
            a1 += __shfl_down(a1, off);
        }
        if (lane == 0) { out[b0] = a0 + b_d[0]; out[b0 + 1] = a1 + b_d[0]; }
    }
}

extern "C" void kernel_launch(void* const* d_in, const int* in_sizes, int n_in,
                              void* d_out, int out_size, void* d_ws, size_t ws_size,
                              hipStream_t stream) {
    const float* x     = (const float*)d_in[0];
    const float* W_ih1 = (const float*)d_in[1];
    const float* W_hh1 = (const float*)d_in[2];
    const float* b_ih1 = (const float*)d_in[3];
    const float* b_hh1 = (const float*)d_in[4];
    const float* W_ih2 = (const float*)d_in[5];
    const float* W_hh2 = (const float*)d_in[6];
    const float* b_ih2 = (const float*)d_in[7];
    const float* b_hh2 = (const float*)d_in[8];
    const float* W_d   = (const float*)d_in[9];
    const float* b_d   = (const float*)d_in[10];

    lstm2_pre<<<NBLK, NTHR, 0, stream>>>(x, W_ih1, W_hh1, b_ih1, b_hh1,
                                         W_ih2, W_hh2, b_ih2, b_hh2,
                                         W_d, b_d, (float*)d_out);
}

// Round 10
// 1317.879 us; speedup vs baseline: 1.2017x; 1.0853x over previous
//
#include <hip/hip_runtime.h>

#define T_SEQ 2048
#define DIN   16
#define HH    80
#define NTHR  512
#define NBLK  256
#define BT    2
#define ROWE  192   // f16 elems per row: [x 0:16 | h1 16:96 | h2 96:176 | pad]

#define L2E   1.44269504088896340736f

typedef _Float16 f16x8 __attribute__((ext_vector_type(8)));
typedef float    f32x4 __attribute__((ext_vector_type(4)));

__device__ __forceinline__ float rcp_fast(float x){ return __builtin_amdgcn_rcpf(x); }
__device__ __forceinline__ float ex2(float x){
#if __has_builtin(__builtin_amdgcn_exp2f)
    return __builtin_amdgcn_exp2f(x);
#else
    return exp2f(x);
#endif
}

#define MFMA16(ac, av, bv) ac = __builtin_amdgcn_mfma_f32_16x16x32_f16(av, bv, ac, 0, 0, 0)

__global__
__attribute__((amdgpu_flat_work_group_size(NTHR, NTHR)))
__attribute__((amdgpu_waves_per_eu(2, 2)))
void lstm2_mfma(
    const float* __restrict__ x,
    const float* __restrict__ W_ih1, const float* __restrict__ W_hh1,
    const float* __restrict__ b_ih1, const float* __restrict__ b_hh1,
    const float* __restrict__ W_ih2, const float* __restrict__ W_hh2,
    const float* __restrict__ b_ih2, const float* __restrict__ b_hh2,
    const float* __restrict__ W_d,   const float* __restrict__ b_d,
    float* __restrict__ out)
{
    __shared__ __align__(16) _Float16 HB[2][BT][ROWE];   // [parity][batch][row]

    const int t    = threadIdx.x;
    const int lane = t & 63;
    const int wv   = t >> 6;              // 0..7 ; wv&3 = SIMD -> each SIMD: 1 L1 + 1 L2 wave
    const bool isL1w = (wv < 4);          // waves 0-3: layer1, 4-7: layer2
    const int m16  = lane & 15;
    const int kgrp = lane >> 4;           // 0..3
    const int b0   = blockIdx.x * BT;

    const int uloc = isL1w ? 20*wv : 20*(wv-4);   // first unit of this wave's 5 tiles

    // ---------------- stationary A fragments (f16 weights, pre-scaled by log2 e) ----------------
    // A row m (=lane&15) within a tile: unit = base + (m>>2), gate = m&3  (i,f,g,o interleave)
    // A col k = 32*chunk + 8*kgrp + j   over concat-K: L1 = [x(16); h1(80)], L2 = [h1(80); h2(80)]
    f16x8 A[5][5];
    {
        const int g  = m16 & 3;
        const int ut = m16 >> 2;
        const float sc = (g == 2) ? (2.f*L2E) : L2E;     // tanh gate needs 2*log2e
        #pragma unroll
        for (int tl = 0; tl < 5; ++tl) {
            const int grow = g*HH + (uloc + 4*tl + ut);  // row in the 320-row weight matrices
            if (isL1w) {
                #pragma unroll
                for (int c = 0; c < 3; ++c) {
                    f16x8 a;
                    #pragma unroll
                    for (int j = 0; j < 8; ++j) {
                        const int k = 32*c + 8*kgrp + j;
                        const float v = (k < DIN) ? W_ih1[grow*DIN + k]
                                                  : W_hh1[grow*HH + (k - DIN)];
                        a[j] = (_Float16)(v * sc);
                    }
                    A[tl][c] = a;
                }
            } else {
                #pragma unroll
                for (int c = 0; c < 5; ++c) {
                    f16x8 a;
                    #pragma unroll
                    for (int j = 0; j < 8; ++j) {
                        const int k = 32*c + 8*kgrp + j;
                        const float v = (k < HH) ? W_ih2[grow*HH + k]
                                                 : W_hh2[grow*HH + (k - HH)];
                        a[j] = (_Float16)(v * sc);
                    }
                    A[tl][c] = a;
                }
            }
        }
    }

    // ---------------- merged-epilogue per-lane identity ----------------
    // C layout: col = lane&15 (batch col, replicated n&1), row = kgrp*4 + r (unit=kgrp, gate=r)
    // lane (m16=2*tl+b) already holds tile tl's correct batch column -> register select only.
    const int  tl_ep    = m16 >> 1;
    const bool act_ep   = (m16 < 10);
    const int  unit_ep  = uloc + 4*(act_ep ? tl_ep : 0) + kgrp;
    const int  batch_ep = lane & 1;
    const int  seg      = isL1w ? DIN : (DIN + HH);      // h1 at 16, h2 at 96
    const float* bI  = isL1w ? b_ih1 : b_ih2;
    const float* bHh = isL1w ? b_hh1 : b_hh2;
    const float bi = (bI[      unit_ep] + bHh[      unit_ep]) * L2E;
    const float bf = (bI[ 80 + unit_ep] + bHh[ 80 + unit_ep]) * L2E;
    const float bg = (bI[160 + unit_ep] + bHh[160 + unit_ep]) * (2.f*L2E);
    const float bo = (bI[240 + unit_ep] + bHh[240 + unit_ep]) * L2E;

    // ---------------- zero h states (both parities), pre-stage x(0) ----------------
    for (int i = t; i < 2*BT*ROWE; i += NTHR) ((_Float16*)HB)[i] = (_Float16)0.f;
    __syncthreads();

    const int xbn = (lane >> 4) & 1;
    const int xch = lane & 15;
    const float* xptr = x + ((size_t)(b0 + xbn) * T_SEQ) * DIN + xch;
    float xa = 0.f, xbv = 0.f, xcv = 0.f;
    if (wv == 0 && lane < 32) {
        HB[0][xbn][xch] = (_Float16)xptr[0];
        xa  = xptr[1*DIN];
        xbv = xptr[2*DIN];
        xcv = xptr[3*DIN];
    }
    __syncthreads();

    // asymmetric static priority (T5 with role diversity): L2 waves (25 MFMA + the
    // critical-path epilogue) win arbitration -> their MFMA burst runs back-to-back and
    // their epilogue overlaps the L1 waves' (deferred) MFMA burst on the matrix pipe.
    if (!isL1w) __builtin_amdgcn_s_setprio(1);

    float cst = 0.f;   // cell state for this lane's (unit,batch) pair

    // window k: L1 computes h1(k) [reads h1(k-1), x(k)]; L2 computes h2(k-1)
    // [reads h1(k-1), h2(k-2)]. Reads parity pb, writes nb.
    #pragma unroll 1
    for (int k = 0; k <= T_SEQ; ++k) {
        const int pb = k & 1, nb = pb ^ 1;

        if (wv == 0 && lane < 32) {          // stage x(k+1) -> nb; refill 3 iters ahead
            HB[nb][xbn][xch] = (_Float16)xa;
            xa = xbv; xbv = xcv;
            const int tn = (k + 4 < T_SEQ) ? (k + 4) : (T_SEQ - 1);
            xcv = xptr[(size_t)tn * DIN];
        }

        const bool act = isL1w ? (k < T_SEQ) : (k >= 1);
        if (act) {
            const _Float16* rb = &HB[pb][lane & 1][0];   // B col n <- batch n&1 (replicated)
            f32x4 acc0 = {0.f,0.f,0.f,0.f}, acc1 = {0.f,0.f,0.f,0.f},
                  acc2 = {0.f,0.f,0.f,0.f}, acc3 = {0.f,0.f,0.f,0.f},
                  acc4 = {0.f,0.f,0.f,0.f};

            if (isL1w) {
                const f16x8 B0 = *(const f16x8*)(rb +       8*kgrp);
                const f16x8 B1 = *(const f16x8*)(rb +  32 + 8*kgrp);
                const f16x8 B2 = *(const f16x8*)(rb +  64 + 8*kgrp);
                MFMA16(acc0, A[0][0], B0); MFMA16(acc0, A[0][1], B1); MFMA16(acc0, A[0][2], B2);
                MFMA16(acc1, A[1][0], B0); MFMA16(acc1, A[1][1], B1); MFMA16(acc1, A[1][2], B2);
                MFMA16(acc2, A[2][0], B0); MFMA16(acc2, A[2][1], B1); MFMA16(acc2, A[2][2], B2);
                MFMA16(acc3, A[3][0], B0); MFMA16(acc3, A[3][1], B1); MFMA16(acc3, A[3][2], B2);
                MFMA16(acc4, A[4][0], B0); MFMA16(acc4, A[4][1], B1); MFMA16(acc4, A[4][2], B2);
            } else {
                const f16x8 B0 = *(const f16x8*)(rb +  16 + 8*kgrp);
                const f16x8 B1 = *(const f16x8*)(rb +  48 + 8*kgrp);
                const f16x8 B2 = *(const f16x8*)(rb +  80 + 8*kgrp);
                const f16x8 B3 = *(const f16x8*)(rb + 112 + 8*kgrp);
                const f16x8 B4 = *(const f16x8*)(rb + 144 + 8*kgrp);
                MFMA16(acc0, A[0][0], B0); MFMA16(acc0, A[0][1], B1); MFMA16(acc0, A[0][2], B2);
                MFMA16(acc0, A[0][3], B3); MFMA16(acc0, A[0][4], B4);
                MFMA16(acc1, A[1][0], B0); MFMA16(acc1, A[1][1], B1); MFMA16(acc1, A[1][2], B2);
                MFMA16(acc1, A[1][3], B3); MFMA16(acc1, A[1][4], B4);
                MFMA16(acc2, A[2][0], B0); MFMA16(acc2, A[2][1], B1); MFMA16(acc2, A[2][2], B2);
                MFMA16(acc2, A[2][3], B3); MFMA16(acc2, A[2][4], B4);
                MFMA16(acc3, A[3][0], B0); MFMA16(acc3, A[3][1], B1); MFMA16(acc3, A[3][2], B2);
                MFMA16(acc3, A[3][3], B3); MFMA16(acc3, A[3][4], B4);
                MFMA16(acc4, A[4][0], B0); MFMA16(acc4, A[4][1], B1); MFMA16(acc4, A[4][2], B2);
                MFMA16(acc4, A[4][3], B3); MFMA16(acc4, A[4][4], B4);
            }

            // in-register merge: pick own tile's (i,f,g,o) — pure cndmask chain
            float M0 = acc0[0], M1 = acc0[1], M2 = acc0[2], M3 = acc0[3];
            if (tl_ep == 1) { M0 = acc1[0]; M1 = acc1[1]; M2 = acc1[2]; M3 = acc1[3]; }
            if (tl_ep == 2) { M0 = acc2[0]; M1 = acc2[1]; M2 = acc2[2]; M3 = acc2[3]; }
            if (tl_ep == 3) { M0 = acc3[0]; M1 = acc3[1]; M2 = acc3[2]; M3 = acc3[3]; }
            if (tl_ep == 4) { M0 = acc4[0]; M1 = acc4[1]; M2 = acc4[2]; M3 = acc4[3]; }

            // activations (pre-acts already scaled by log2e / 2*log2e)
            const float gi = M0 + bi, gf = M1 + bf, gg = M2 + bg, go = M3 + bo;
            const float iv = rcp_fast(1.f + ex2(-gi));
            const float fv = rcp_fast(1.f + ex2(-gf));
            const float ov = rcp_fast(1.f + ex2(-go));
            const float gv = 1.f - 2.f*rcp_fast(1.f + ex2(gg));
            cst = fv*cst + iv*gv;
            const float tc = 1.f - 2.f*rcp_fast(1.f + ex2(cst * (2.f*L2E)));
            if (act_ep) HB[nb][batch_ep][seg + unit_ep] = (_Float16)(ov * tc);
        }
        __syncthreads();
    }

    // ---------------- dense head: out[b] = W_d . h2(T-1) + b_d ; final h2 in parity 1 ----------------
    if (wv == 0) {
        float a0 = 0.f, a1 = 0.f;
        for (int u = lane; u < HH; u += 64) {
            const float wd = W_d[u];
            a0 += wd * (float)HB[1][0][DIN + HH + u];
            a1 += wd * (float)HB[1][1][DIN + HH + u];
        }
        #pragma unroll
        for (int off = 32; off > 0; off >>= 1) {
            a0 += __shfl_down(a0, off);
            a1 += __shfl_down(a1, off);
        }
        if (lane == 0) { out[b0] = a0 + b_d[0]; out[b0 + 1] = a1 + b_d[0]; }
    }
}

extern "C" void kernel_launch(void* const* d_in, const int* in_sizes, int n_in,
                              void* d_out, int out_size, void* d_ws, size_t ws_size,
                              hipStream_t stream) {
    const float* x     = (const float*)d_in[0];
    const float* W_ih1 = (const float*)d_in[1];
    const float* W_hh1 = (const float*)d_in[2];
    const float* b_ih1 = (const float*)d_in[3];
    const float* b_hh1 = (const float*)d_in[4];
    const float* W_ih2 = (const float*)d_in[5];
    const float* W_hh2 = (const float*)d_in[6];
    const float* b_ih2 = (const float*)d_in[7];
    const float* b_hh2 = (const float*)d_in[8];
    const float* W_d   = (const float*)d_in[9];
    const float* b_d   = (const float*)d_in[10];

    lstm2_mfma<<<NBLK, NTHR, 0, stream>>>(x, W_ih1, W_hh1, b_ih1, b_hh1,
                                          W_ih2, W_hh2, b_ih2, b_hh2,
                                          W_d, b_d, (float*)d_out);
}